// Round 6
// baseline (503.321 us; speedup 1.0000x reference)
//
#include <hip/hip_runtime.h>
#include <cstdint>
#include <cstddef>

// Problem constants
#define N_TOK 4096     // B*T tokens
#define DM    1024     // d_model
#define DH    2048     // d_hidden
#define NE    8        // experts
#define NSLOT 8192     // total routed slots = N_TOK * top_k

typedef short bf16x8_t __attribute__((ext_vector_type(8)));  // 8 bf16 (4 VGPRs)
typedef float f32x4    __attribute__((ext_vector_type(4)));
typedef unsigned short u16x8 __attribute__((ext_vector_type(8)));

__device__ __forceinline__ unsigned short f2bf(float f) {
  union { float f; unsigned int u; } v; v.f = f;
  unsigned int u = v.u;
  u += 0x7fffu + ((u >> 16) & 1u);   // RNE
  return (unsigned short)(u >> 16);
}

__device__ __forceinline__ float bf2f(unsigned short h) {
  union { unsigned int u; float f; } v; v.u = ((unsigned int)h) << 16;
  return v.f;
}

#define GLD16(gp, lp)                                                          \
  __builtin_amdgcn_global_load_lds(                                            \
      (const __attribute__((address_space(1))) void*)(gp),                     \
      (__attribute__((address_space(3))) void*)(lp), 16, 0, 0)

// prefix-from-counts helper: returns offset of expert e, sets cnt
__device__ __forceinline__ int expert_off(const int* __restrict__ counts, int e, int* cnt) {
  int off = 0, s = 0;
#pragma unroll
  for (int i = 0; i < NE; i++) { if (i == e) off = s; s += counts[i]; }
  *cnt = counts[e];
  return off;
}

// ---------------------------------------------------------------------------
// Fused transpose + fp32->bf16 for all three weight tensors in ONE launch.
// grid = (32, 16, 24): z<8 -> W, z<16 -> V (both [DM][DH] -> B1t rows),
// z>=16 -> Wout ([DH][DM] -> B2t). 64x64 tiles, float4 reads, 16B writes.
// Block (0,0,0) also zeroes counts (router runs later on the same stream).
// ---------------------------------------------------------------------------
__global__ __launch_bounds__(256) void k_transpose(
    const float* __restrict__ W, const float* __restrict__ V,
    const float* __restrict__ Wout, unsigned short* __restrict__ B1t,
    unsigned short* __restrict__ B2t, int* __restrict__ counts) {
  if (blockIdx.z == 0 && blockIdx.x == 0 && blockIdx.y == 0 && threadIdx.x < NE)
    counts[threadIdx.x] = 0;

  const int z = blockIdx.z;
  const float* s;
  unsigned short* d;
  int R, C, xt, yt;
  if (z < 16) {
    const int e = z & 7;
    s = ((z < 8) ? W : V) + (size_t)e * DM * DH;
    d = B1t + (size_t)e * 4096 * DM + (size_t)((z < 8) ? 0 : DH) * DM;
    R = DM; C = DH; xt = blockIdx.x; yt = blockIdx.y;      // 32 x 16 tiles
  } else {
    const int e = z - 16;
    s = Wout + (size_t)e * DH * DM;
    d = B2t + (size_t)e * DM * DH;
    R = DH; C = DM;
    const int flat = blockIdx.x * 16 + blockIdx.y;          // 0..511 = 16 x 32
    xt = flat & 15; yt = flat >> 4;
  }
  const int c0 = xt * 64, r0 = yt * 64;
  __shared__ float tile[64][65];
  const int t = threadIdx.x;
  {
    const int cc = (t & 15) * 4;
#pragma unroll
    for (int j = 0; j < 4; j++) {
      const int r = (t >> 4) + j * 16;
      const float4 v = *(const float4*)(s + (size_t)(r0 + r) * C + c0 + cc);
      tile[r][cc + 0] = v.x; tile[r][cc + 1] = v.y;
      tile[r][cc + 2] = v.z; tile[r][cc + 3] = v.w;
    }
  }
  __syncthreads();
  {
    const int r8 = (t & 7) * 8;
#pragma unroll
    for (int j = 0; j < 2; j++) {
      const int c = (t >> 3) + j * 32;
      u16x8 o;
#pragma unroll
      for (int i = 0; i < 8; i++) o[i] = f2bf(tile[r8 + i][c]);
      *(u16x8*)(d + (size_t)(c0 + c) * R + r0 + r8) = o;
    }
  }
}

// ---------------------------------------------------------------------------
// Router: fp32 logits, top-2, softmax, atomic per-expert slot assignment.
// One wave per token.
// ---------------------------------------------------------------------------
__global__ __launch_bounds__(256) void k_router(
    const float* __restrict__ x, const float* __restrict__ rw,
    const float* __restrict__ rb, int* __restrict__ counts,
    int* __restrict__ meta_e, int* __restrict__ meta_idx,
    float* __restrict__ meta_p) {
  const int wv = threadIdx.x >> 6;
  const int l  = threadIdx.x & 63;
  const int tk = blockIdx.x * 4 + wv;
  const float* xr = x + (size_t)tk * DM;

  float acc[NE];
#pragma unroll
  for (int e = 0; e < NE; e++) acc[e] = 0.f;
#pragma unroll 4
  for (int i = 0; i < DM / 64; i++) {
    const float xv = xr[i * 64 + l];
#pragma unroll
    for (int e = 0; e < NE; e++) acc[e] += xv * rw[e * DM + i * 64 + l];
  }
#pragma unroll
  for (int off = 32; off > 0; off >>= 1) {
#pragma unroll
    for (int e = 0; e < NE; e++) acc[e] += __shfl_xor(acc[e], off);
  }
#pragma unroll
  for (int e = 0; e < NE; e++) acc[e] += rb[e];

  // top-2, strict > ascending scan (ties -> lower index, matches top_k)
  float v0 = -1e30f; int e0 = 0;
#pragma unroll
  for (int e = 0; e < NE; e++) { if (acc[e] > v0) { v0 = acc[e]; e0 = e; } }
  float v1 = -1e30f; int e1 = 0;
#pragma unroll
  for (int e = 0; e < NE; e++) { if (e != e0 && acc[e] > v1) { v1 = acc[e]; e1 = e; } }
  const float p0 = 1.0f / (1.0f + __expf(v1 - v0));
  const float p1 = 1.0f - p0;

  if (l == 0) {
    const int i0 = atomicAdd(&counts[e0], 1);
    const int i1 = atomicAdd(&counts[e1], 1);
    meta_e[tk * 2 + 0] = e0;  meta_e[tk * 2 + 1] = e1;
    meta_idx[tk * 2 + 0] = i0; meta_idx[tk * 2 + 1] = i1;
    meta_p[tk * 2 + 0] = p0;  meta_p[tk * 2 + 1] = p1;
  }
}

// ---------------------------------------------------------------------------
// Gather: one block per TOKEN; read x row once, write both routed slots.
// ---------------------------------------------------------------------------
__global__ __launch_bounds__(256) void k_gather(
    const float* __restrict__ x, const int* __restrict__ meta_e,
    const int* __restrict__ meta_idx, const int* __restrict__ counts,
    unsigned short* __restrict__ Xg) {
  const int tk = blockIdx.x;
  int offs[NE];
  { int s = 0;
#pragma unroll
    for (int e = 0; e < NE; e++) { offs[e] = s; s += counts[e]; } }
  const int s0 = tk * 2, s1 = s0 + 1;
  const int g0 = offs[meta_e[s0]] + meta_idx[s0];
  const int g1 = offs[meta_e[s1]] + meta_idx[s1];
  const float4 v = ((const float4*)(x + (size_t)tk * DM))[threadIdx.x];
  ushort4 o;
  o.x = f2bf(v.x); o.y = f2bf(v.y); o.z = f2bf(v.z); o.w = f2bf(v.w);
  *(ushort4*)(Xg + (size_t)g0 * DM + threadIdx.x * 4) = o;
  *(ushort4*)(Xg + (size_t)g1 * DM + threadIdx.x * 4) = o;
}

// ---------------------------------------------------------------------------
// GEMM1 fused SwiGLU. Tile 128m x 64n, BK=64 (two 32-k sub-tiles).
// Smaller tile halves acc regs (64/thread) -> 3 blocks/CU (12 waves) via
// __launch_bounds__(256,3): raises latency hiding vs the 2-block 128x128.
// Wave-tile 64m x 32n (4 waves, 2x2). Epilogue g = a * silu(b) -> G bf16.
// ---------------------------------------------------------------------------
__global__ __launch_bounds__(256, 3) void k_gemm1(
    const unsigned short* __restrict__ Xg, const unsigned short* __restrict__ B1t,
    unsigned short* __restrict__ G, const int* __restrict__ counts) {
  const int e = blockIdx.z;
  int cnt;
  const int off = expert_off(counts, e, &cnt);
  const int mt = blockIdx.y;
  if (mt * 128 >= cnt) return;
  const int h0 = blockIdx.x * 64;
  const int row_base = off + mt * 128;

  __shared__ unsigned short As[2][128 * 32];
  __shared__ unsigned short Ws[2][64 * 32];
  __shared__ unsigned short Vs[2][64 * 32];

  const int t = threadIdx.x;
  const int l = t & 63;
  const int w = t >> 6;
  const int wm = (w & 1) * 64;       // wave m-offset
  const int wn = (w >> 1) * 32;      // wave n-offset
  const int lr = l & 15;
  const int kq = (l >> 4) * 8;

  const unsigned short* Bw = B1t + ((size_t)e * 4096 + h0) * DM;
  const unsigned short* Bv = Bw + (size_t)DH * DM;

  // A staging: rows t>>2 and t>>2+64, koff (t&3)*8 ; LDS elem offset = c*8
  const int ar0 = t >> 2, ak0 = (t & 3) * 8;
  const int arow0 = min(row_base + ar0, NSLOT - 1);       // clamp: no OOB
  const int arow1 = min(row_base + ar0 + 64, NSLOT - 1);
  // B staging: row t>>2 (0..63), koff (t&3)*8
  const int br = t >> 2, bk = (t & 3) * 8;

  f32x4 acc_a[4][2], acc_b[4][2];
  const f32x4 z4 = {0.f, 0.f, 0.f, 0.f};
#pragma unroll
  for (int i = 0; i < 4; i++)
#pragma unroll
    for (int j = 0; j < 2; j++) { acc_a[i][j] = z4; acc_b[i][j] = z4; }

  for (int k0 = 0; k0 < DM; k0 += 64) {
    __syncthreads();
    GLD16(Xg + (size_t)arow0 * DM + k0 + ak0,      &As[0][t * 8]);
    GLD16(Xg + (size_t)arow1 * DM + k0 + ak0,      &As[0][(t + 256) * 8]);
    GLD16(Xg + (size_t)arow0 * DM + k0 + 32 + ak0, &As[1][t * 8]);
    GLD16(Xg + (size_t)arow1 * DM + k0 + 32 + ak0, &As[1][(t + 256) * 8]);
    GLD16(Bw + (size_t)br * DM + k0 + bk,          &Ws[0][t * 8]);
    GLD16(Bw + (size_t)br * DM + k0 + 32 + bk,     &Ws[1][t * 8]);
    GLD16(Bv + (size_t)br * DM + k0 + bk,          &Vs[0][t * 8]);
    GLD16(Bv + (size_t)br * DM + k0 + 32 + bk,     &Vs[1][t * 8]);
    __syncthreads();

#pragma unroll
    for (int ks = 0; ks < 2; ks++) {
      bf16x8_t af[4], wf[2], vf[2];
#pragma unroll
      for (int mi = 0; mi < 4; mi++)
        af[mi] = *(const bf16x8_t*)&As[ks][(wm + mi * 16 + lr) * 32 + kq];
#pragma unroll
      for (int ni = 0; ni < 2; ni++) {
        wf[ni] = *(const bf16x8_t*)&Ws[ks][(wn + ni * 16 + lr) * 32 + kq];
        vf[ni] = *(const bf16x8_t*)&Vs[ks][(wn + ni * 16 + lr) * 32 + kq];
      }
#pragma unroll
      for (int mi = 0; mi < 4; mi++)
#pragma unroll
        for (int ni = 0; ni < 2; ni++) {
          acc_a[mi][ni] = __builtin_amdgcn_mfma_f32_16x16x32_bf16(af[mi], wf[ni], acc_a[mi][ni], 0, 0, 0);
          acc_b[mi][ni] = __builtin_amdgcn_mfma_f32_16x16x32_bf16(af[mi], vf[ni], acc_b[mi][ni], 0, 0, 0);
        }
    }
  }

  const int q4 = (l >> 4) * 4;
#pragma unroll
  for (int mi = 0; mi < 4; mi++) {
#pragma unroll
    for (int r = 0; r < 4; r++) {
      const int mloc = mt * 128 + wm + mi * 16 + q4 + r;
      if (mloc >= cnt) continue;
      unsigned short* grow = G + (size_t)(off + mloc) * DH;
#pragma unroll
      for (int ni = 0; ni < 2; ni++) {
        const int h = h0 + wn + ni * 16 + lr;
        const float a = acc_a[mi][ni][r];
        const float b = acc_b[mi][ni][r];
        const float s = b / (1.0f + __expf(-b));  // silu(b)
        grow[h] = f2bf(a * s);
      }
    }
  }
}

// ---------------------------------------------------------------------------
// GEMM2: Y = G @ W_out^T. Tile 128m x 64n, BK=64, full K=2048 (split-K
// dropped: 1024 active blocks at 3/CU is enough). bf16 Y, single copy.
// ---------------------------------------------------------------------------
__global__ __launch_bounds__(256, 3) void k_gemm2(
    const unsigned short* __restrict__ G, const unsigned short* __restrict__ B2t,
    unsigned short* __restrict__ Y, const int* __restrict__ counts) {
  const int e = blockIdx.z;
  int cnt;
  const int off = expert_off(counts, e, &cnt);
  const int mt = blockIdx.y;
  if (mt * 128 >= cnt) return;
  const int n0 = blockIdx.x * 64;
  const int row_base = off + mt * 128;

  __shared__ unsigned short As[2][128 * 32];
  __shared__ unsigned short Bs[2][64 * 32];

  const int t = threadIdx.x;
  const int l = t & 63;
  const int w = t >> 6;
  const int wm = (w & 1) * 64;
  const int wn = (w >> 1) * 32;
  const int lr = l & 15;
  const int kq = (l >> 4) * 8;

  const unsigned short* Bp = B2t + ((size_t)e * DM + n0) * DH;

  const int ar0 = t >> 2, ak0 = (t & 3) * 8;
  const int arow0 = min(row_base + ar0, NSLOT - 1);
  const int arow1 = min(row_base + ar0 + 64, NSLOT - 1);
  const int br = t >> 2, bk = (t & 3) * 8;

  f32x4 acc[4][2];
  const f32x4 z4 = {0.f, 0.f, 0.f, 0.f};
#pragma unroll
  for (int i = 0; i < 4; i++)
#pragma unroll
    for (int j = 0; j < 2; j++) acc[i][j] = z4;

  for (int k0 = 0; k0 < DH; k0 += 64) {
    __syncthreads();
    GLD16(G + (size_t)arow0 * DH + k0 + ak0,      &As[0][t * 8]);
    GLD16(G + (size_t)arow1 * DH + k0 + ak0,      &As[0][(t + 256) * 8]);
    GLD16(G + (size_t)arow0 * DH + k0 + 32 + ak0, &As[1][t * 8]);
    GLD16(G + (size_t)arow1 * DH + k0 + 32 + ak0, &As[1][(t + 256) * 8]);
    GLD16(Bp + (size_t)br * DH + k0 + bk,         &Bs[0][t * 8]);
    GLD16(Bp + (size_t)br * DH + k0 + 32 + bk,    &Bs[1][t * 8]);
    __syncthreads();

#pragma unroll
    for (int ks = 0; ks < 2; ks++) {
      bf16x8_t af[4], bf[2];
#pragma unroll
      for (int mi = 0; mi < 4; mi++)
        af[mi] = *(const bf16x8_t*)&As[ks][(wm + mi * 16 + lr) * 32 + kq];
#pragma unroll
      for (int ni = 0; ni < 2; ni++)
        bf[ni] = *(const bf16x8_t*)&Bs[ks][(wn + ni * 16 + lr) * 32 + kq];
#pragma unroll
      for (int mi = 0; mi < 4; mi++)
#pragma unroll
        for (int ni = 0; ni < 2; ni++)
          acc[mi][ni] = __builtin_amdgcn_mfma_f32_16x16x32_bf16(af[mi], bf[ni], acc[mi][ni], 0, 0, 0);
    }
  }

  const int q4 = (l >> 4) * 4;
#pragma unroll
  for (int mi = 0; mi < 4; mi++) {
#pragma unroll
    for (int r = 0; r < 4; r++) {
      const int mloc = mt * 128 + wm + mi * 16 + q4 + r;
      if (mloc >= cnt) continue;
      unsigned short* yrow = Y + (size_t)(off + mloc) * DM;
#pragma unroll
      for (int ni = 0; ni < 2; ni++)
        yrow[n0 + wn + ni * 16 + lr] = f2bf(acc[mi][ni][r]);
    }
  }
}

// ---------------------------------------------------------------------------
// Combine: out[tok] = p0 * Y[g0] + p1 * Y[g1]; Y is bf16 [NSLOT][DM].
// ---------------------------------------------------------------------------
__global__ __launch_bounds__(256) void k_combine(
    const unsigned short* __restrict__ Y, const int* __restrict__ meta_e,
    const int* __restrict__ meta_idx, const float* __restrict__ meta_p,
    const int* __restrict__ counts, float* __restrict__ out) {
  const int tk = blockIdx.x;
  int offs[NE];
  { int s = 0;
#pragma unroll
    for (int e = 0; e < NE; e++) { offs[e] = s; s += counts[e]; } }
  const int s0 = tk * 2, s1 = s0 + 1;
  const int g0 = offs[meta_e[s0]] + meta_idx[s0];
  const int g1 = offs[meta_e[s1]] + meta_idx[s1];
  const float w0 = meta_p[s0], w1 = meta_p[s1];
  const ushort4 a = ((const ushort4*)(Y + (size_t)g0 * DM))[threadIdx.x];
  const ushort4 b = ((const ushort4*)(Y + (size_t)g1 * DM))[threadIdx.x];
  float4 o;
  o.x = w0 * bf2f(a.x) + w1 * bf2f(b.x);
  o.y = w0 * bf2f(a.y) + w1 * bf2f(b.y);
  o.z = w0 * bf2f(a.z) + w1 * bf2f(b.z);
  o.w = w0 * bf2f(a.w) + w1 * bf2f(b.w);
  ((float4*)(out + (size_t)tk * DM))[threadIdx.x] = o;
}

// ---------------------------------------------------------------------------
extern "C" void kernel_launch(void* const* d_in, const int* in_sizes, int n_in,
                              void* d_out, int out_size, void* d_ws, size_t ws_size,
                              hipStream_t stream) {
  const float* x    = (const float*)d_in[0];  // [2,2048,1024]
  const float* rw   = (const float*)d_in[1];  // [8,1024]
  const float* rb   = (const float*)d_in[2];  // [8]
  const float* W    = (const float*)d_in[3];  // [8,1024,2048]
  const float* V    = (const float*)d_in[4];  // [8,1024,2048]
  const float* Wout = (const float*)d_in[5];  // [8,2048,1024]
  float* out = (float*)d_out;

  // workspace carve-up (~145 MB); Y (bf16 [NSLOT][DM] = 16 MB) aliases B1t
  // (64 MB, dead after gemm1)
  char* p = (char*)d_ws;
  unsigned short* B1t = (unsigned short*)p; p += (size_t)NE * 4096 * DM * 2;   // 64 MB [e][n=4096][k=1024]
  unsigned short* Y   = (unsigned short*)B1t;                                  // alias: [NSLOT][DM] bf16
  unsigned short* B2t = (unsigned short*)p; p += (size_t)NE * DM * DH * 2;     // 32 MB [e][n=1024][k=2048]
  unsigned short* Xg  = (unsigned short*)p; p += (size_t)NSLOT * DM * 2;       // 16 MB
  unsigned short* G   = (unsigned short*)p; p += (size_t)NSLOT * DH * 2;       // 32 MB
  int*   counts      = (int*)p;   p += 256;
  int*   meta_e      = (int*)p;   p += (size_t)N_TOK * 2 * 4;
  int*   meta_idx    = (int*)p;   p += (size_t)N_TOK * 2 * 4;
  float* meta_p      = (float*)p; p += (size_t)N_TOK * 2 * 4;

  k_transpose<<<dim3(32, 16, 24), 256, 0, stream>>>(W, V, Wout, B1t, B2t, counts);
  k_router<<<N_TOK / 4, 256, 0, stream>>>(x, rw, rb, counts, meta_e, meta_idx, meta_p);
  k_gather<<<N_TOK, 256, 0, stream>>>(x, meta_e, meta_idx, counts, Xg);
  k_gemm1<<<dim3(DH / 64, NSLOT / 128, NE), 256, 0, stream>>>(Xg, B1t, G, counts);
  k_gemm2<<<dim3(DM / 64, NSLOT / 128, NE), 256, 0, stream>>>(G, B2t, Y, counts);
  k_combine<<<N_TOK, 256, 0, stream>>>(Y, meta_e, meta_idx, meta_p, counts, out);
}